// Round 1
// baseline (2583.594 us; speedup 1.0000x reference)
//
#include <hip/hip_runtime.h>
#include <cstdint>
#include <cstddef>

#define HW 16384  // 128*128

// ---------------- conv1 + fire(15) + maxpool 2x2 ----------------
// grid (64 tiles, 30 oc, 15 t), block 256 (16x16), each thread -> 1 pooled pixel (2x2 conv outs)
__global__ __launch_bounds__(256) void k_conv1(const float* __restrict__ x,
                                               const float* __restrict__ w1,
                                               uint8_t* __restrict__ spk_pool) {
  const int tile = blockIdx.x, oc = blockIdx.y, t = blockIdx.z;
  const int tx = threadIdx.x & 15, ty = threadIdx.x >> 4;
  const int px0 = (tile & 7) << 4, py0 = (tile >> 3) << 4;  // pooled tile origin
  __shared__ float sx[36][37];
  __shared__ float wS[25];
  float acc00 = 0.f, acc01 = 0.f, acc10 = 0.f, acc11 = 0.f;
  const int iy0 = (py0 << 1) - 2, ix0 = (px0 << 1) - 2;  // input tile origin (pad=2)
  for (int ic = 0; ic < 6; ++ic) {
    if (threadIdx.x < 25) wS[threadIdx.x] = w1[(oc * 6 + ic) * 25 + threadIdx.x];
    const float* xp = x + ((size_t)(t * 6 + ic) << 16);
    for (int i = threadIdx.x; i < 36 * 36; i += 256) {
      int r = i / 36, c = i - r * 36;
      int gy = iy0 + r, gx = ix0 + c;
      float v = 0.f;
      if ((unsigned)gy < 256u && (unsigned)gx < 256u) v = xp[(gy << 8) + gx];
      sx[r][c] = v;
    }
    __syncthreads();
#pragma unroll
    for (int ky = 0; ky < 5; ++ky)
#pragma unroll
      for (int kx = 0; kx < 5; ++kx) {
        float w = wS[ky * 5 + kx];
        acc00 += w * sx[2 * ty + ky][2 * tx + kx];
        acc01 += w * sx[2 * ty + ky][2 * tx + 1 + kx];
        acc10 += w * sx[2 * ty + 1 + ky][2 * tx + kx];
        acc11 += w * sx[2 * ty + 1 + ky][2 * tx + 1 + kx];
      }
    __syncthreads();
  }
  int spike = (acc00 > 15.f) || (acc01 > 15.f) || (acc10 > 15.f) || (acc11 > 15.f);
  spk_pool[((size_t)(t * 30 + oc) << 14) + ((size_t)(py0 + ty) << 7) + (px0 + tx)] =
      (uint8_t)spike;
}

// ---------------- conv2 (pad=1) + fire(10) -> pot2 (NCHW, into pot out region) ----------------
// grid (4 tiles, 250 oc, 15 t), block 256 (16x16 threads, 4x4 outputs each -> 64x64 tile)
__global__ __launch_bounds__(256) void k_conv2(const uint8_t* __restrict__ spk_pool,
                                               const float* __restrict__ w2,
                                               float* __restrict__ pot2) {
  const int tile = blockIdx.x, oc = blockIdx.y, t = blockIdx.z;
  const int bx = (tile & 1) << 6, by = (tile >> 1) << 6;
  const int tx = threadIdx.x & 15, ty = threadIdx.x >> 4;
  __shared__ __align__(16) float sS[66][68];
  __shared__ float wS[272];
  for (int i = threadIdx.x; i < 270; i += 256) wS[i] = w2[oc * 270 + i];
  float acc[4][4];
#pragma unroll
  for (int r = 0; r < 4; ++r)
#pragma unroll
    for (int s = 0; s < 4; ++s) acc[r][s] = 0.f;
  const int iy0 = by - 1, ix0 = bx - 1;
  for (int ic = 0; ic < 30; ++ic) {
    const uint8_t* spc = spk_pool + ((size_t)(t * 30 + ic) << 14);
    for (int i = threadIdx.x; i < 66 * 66; i += 256) {
      int r = i / 66, c = i - r * 66;
      int gy = iy0 + r, gx = ix0 + c;
      float v = 0.f;
      if ((unsigned)gy < 128u && (unsigned)gx < 128u) v = (float)spc[(gy << 7) + gx];
      sS[r][c] = v;
    }
    __syncthreads();
    float w_[9];
#pragma unroll
    for (int k = 0; k < 9; ++k) w_[k] = wS[ic * 9 + k];
    float win_[6][6];
#pragma unroll
    for (int r = 0; r < 6; ++r) {
      float4 a = *(const float4*)&sS[ty * 4 + r][tx * 4];
      float2 b = *(const float2*)&sS[ty * 4 + r][tx * 4 + 4];
      win_[r][0] = a.x; win_[r][1] = a.y; win_[r][2] = a.z; win_[r][3] = a.w;
      win_[r][4] = b.x; win_[r][5] = b.y;
    }
#pragma unroll
    for (int r = 0; r < 4; ++r)
#pragma unroll
      for (int s = 0; s < 4; ++s) {
        float a = acc[r][s];
        a += w_[0] * win_[r][s]     + w_[1] * win_[r][s + 1]     + w_[2] * win_[r][s + 2];
        a += w_[3] * win_[r + 1][s] + w_[4] * win_[r + 1][s + 1] + w_[5] * win_[r + 1][s + 2];
        a += w_[6] * win_[r + 2][s] + w_[7] * win_[r + 2][s + 1] + w_[8] * win_[r + 2][s + 2];
        acc[r][s] = a;
      }
    __syncthreads();
  }
  float* outp = pot2 + ((size_t)(t * 250 + oc) << 14);
#pragma unroll
  for (int r = 0; r < 4; ++r) {
    int gy = by + ty * 4 + r;
    float4 v;
    v.x = acc[r][0] > 10.f ? acc[r][0] : 0.f;
    v.y = acc[r][1] > 10.f ? acc[r][1] : 0.f;
    v.z = acc[r][2] > 10.f ? acc[r][2] : 0.f;
    v.w = acc[r][3] > 10.f ? acc[r][3] : 0.f;
    *(float4*)&outp[((size_t)gy << 7) + bx + tx * 4] = v;
  }
}

// ---------------- per-(t,loc) channel max + argmax (first occurrence) ----------------
// grid (64, 15), block 256
__global__ __launch_bounds__(256) void k_chanmax(const float* __restrict__ pot2,
                                                 float* __restrict__ mx,
                                                 int* __restrict__ am) {
  const int t = blockIdx.y;
  const int loc = (blockIdx.x << 8) + threadIdx.x;
  const float* p = pot2 + ((size_t)(t * 250) << 14) + loc;
  float best = p[0];
  int bi = 0;
#pragma unroll 5
  for (int c = 1; c < 250; ++c) {
    float v = p[(size_t)c << 14];
    if (v > best) { best = v; bi = c; }
  }
  mx[t * HW + loc] = best;
  am[t * HW + loc] = bi;
}

// ---------------- inhibition combine per location ----------------
// grid (64), block 256
__global__ __launch_bounds__(256) void k_inhib(const float* __restrict__ pot2,
                                               const float* __restrict__ mx,
                                               const int* __restrict__ am,
                                               int* __restrict__ win,
                                               float* __restrict__ nspv,
                                               float* __restrict__ valv,
                                               float* __restrict__ sv) {
  const int loc = (blockIdx.x << 8) + threadIdx.x;
  int cnt = 0;
#pragma unroll
  for (int t = 0; t < 15; ++t) cnt += (mx[t * HW + loc] > 0.f) ? 1 : 0;
  const int spiked = (mx[14 * HW + loc] > 0.f) ? 1 : 0;
  int ft = 15 - cnt;
  if (ft > 14) ft = 14;
  if (ft < 0) ft = 0;
  const int wc = am[ft * HW + loc];
  int nsp = 0;
#pragma unroll
  for (int t = 0; t < 15; ++t) {
    float v = pot2[((size_t)(t * 250 + wc) << 14) + loc];
    v = spiked ? v : 0.f;  // post-inhibition value at winner channel
    sv[t * HW + loc] = v;
    nsp += (v > 0.f) ? 1 : 0;
  }
  int ft2 = 15 - nsp;
  if (ft2 > 14) ft2 = 14;
  float value = spiked ? pot2[((size_t)(ft2 * 250 + wc) << 14) + loc] : 0.f;
  win[loc] = spiked ? wc : -1;
  nspv[loc] = (float)nsp;
  valv[loc] = value;
}

// ---------------- scatter winner-channel values into zeroed outputs ----------------
// grid (64), block 256
__global__ __launch_bounds__(256) void k_scatter(const int* __restrict__ win,
                                                 const float* __restrict__ sv,
                                                 float* __restrict__ spk_out,
                                                 float* __restrict__ pot_out) {
  const int loc = (blockIdx.x << 8) + threadIdx.x;
  const int wc = win[loc];
  if (wc < 0) return;
#pragma unroll
  for (int t = 0; t < 15; ++t) {
    float v = sv[t * HW + loc];
    size_t idx = ((size_t)(t * 250 + wc) << 14) + loc;
    pot_out[idx] = v;
    spk_out[idx] = (v > 0.f) ? 1.f : 0.f;
  }
}

// ---------------- k-winner selection (single block, total kept sparse per-location) ----------
__global__ __launch_bounds__(256) void k_select(const int* __restrict__ win,
                                                const float* __restrict__ nspv,
                                                const float* __restrict__ valv,
                                                float* __restrict__ winners) {
  __shared__ float tot[HW];   // 64 KB
  __shared__ int wchan[HW];   // 64 KB
  __shared__ float redV[256];
  __shared__ int redK[256];
  __shared__ float bcValid[1];
  __shared__ int bcKey[1];
  const int tid = threadIdx.x;

  // v = T * max(spikes*values) ; value>0 <=> nspikes>0, values>=0 -> v = 15*max(valv)
  float lmax = 0.f;
  for (int i = tid; i < HW; i += 256) {
    wchan[i] = win[i];
    lmax = fmaxf(lmax, valv[i]);
  }
  redV[tid] = lmax;
  __syncthreads();
  for (int s = 128; s > 0; s >>= 1) {
    if (tid < s) redV[tid] = fmaxf(redV[tid], redV[tid + s]);
    __syncthreads();
  }
  const float v15 = redV[0] * 15.f;
  __syncthreads();
  for (int i = tid; i < HW; i += 256) tot[i] = nspv[i] * (valv[i] + v15);
  __syncthreads();

  for (int k = 0; k < 8; ++k) {
    // argmax over flat (C,H,W) order; tie -> smallest flat index (c major)
    float bv = -1.f;
    int bkey = 0x7fffffff;
    for (int i = tid; i < HW; i += 256) {
      float v = tot[i];
      int key = (wchan[i] << 14) + i;  // v>0 implies wchan>=0
      if (v > bv || (v == bv && key < bkey)) { bv = v; bkey = key; }
    }
    redV[tid] = bv;
    redK[tid] = bkey;
    __syncthreads();
    for (int s = 128; s > 0; s >>= 1) {
      if (tid < s) {
        float ov = redV[tid + s];
        int ok = redK[tid + s];
        if (ov > redV[tid] || (ov == redV[tid] && ok < redK[tid])) {
          redV[tid] = ov;
          redK[tid] = ok;
        }
      }
      __syncthreads();
    }
    if (tid == 0) {
      float mv = redV[0];
      int mk = redK[0];
      int valid = (mv != 0.f) ? 1 : 0;
      int c = mk >> 14, l = mk & (HW - 1);
      winners[k * 3 + 0] = valid ? (float)c : -1.f;
      winners[k * 3 + 1] = valid ? (float)(l >> 7) : -1.f;
      winners[k * 3 + 2] = valid ? (float)(l & 127) : -1.f;
      bcValid[0] = valid ? 1.f : 0.f;
      bcKey[0] = mk;
    }
    __syncthreads();
    if (bcValid[0] > 0.f) {
      int mk = bcKey[0];
      int c = mk >> 14, h = (mk & (HW - 1)) >> 7, w = mk & 127;
      for (int i = tid; i < HW; i += 256) {
        int hh = i >> 7, ww = i & 127;
        int dh = hh - h; if (dh < 0) dh = -dh;
        int dw = ww - w; if (dw < 0) dw = -dw;
        bool m = (wchan[i] == c) || (dh <= 1 && dw <= 1);
        if (m) tot[i] = 0.f;
      }
    }
    __syncthreads();
  }
}

extern "C" void kernel_launch(void* const* d_in, const int* in_sizes, int n_in,
                              void* d_out, int out_size, void* d_ws, size_t ws_size,
                              hipStream_t stream) {
  const float* x = (const float*)d_in[0];
  const float* w1 = (const float*)d_in[1];
  const float* w2 = (const float*)d_in[2];
  (void)in_sizes; (void)n_in; (void)out_size; (void)ws_size;

  float* spk_out = (float*)d_out;
  float* pot_out = spk_out + 61440000;      // also used as pot2 scratch (final pot == pot2 at winner ch)
  float* winners = spk_out + 122880000;

  uint8_t* ws = (uint8_t*)d_ws;
  uint8_t* spk_pool = ws;                   //  7,372,800 B  u8 [15][30][128][128]
  float* mx = (float*)(ws + 7372800);       //    983,040 B  [15][16384]
  int* am = (int*)(ws + 8355840);           //    983,040 B  [15][16384]
  int* win = (int*)(ws + 9338880);          //     65,536 B  [16384]
  float* nspv = (float*)(ws + 9404416);     //     65,536 B
  float* valv = (float*)(ws + 9469952);     //     65,536 B
  float* sv = (float*)(ws + 9535488);       //    983,040 B  [15][16384]

  hipLaunchKernelGGL(k_conv1, dim3(64, 30, 15), dim3(256), 0, stream, x, w1, spk_pool);
  hipLaunchKernelGGL(k_conv2, dim3(4, 250, 15), dim3(256), 0, stream, spk_pool, w2, pot_out);
  hipLaunchKernelGGL(k_chanmax, dim3(64, 15), dim3(256), 0, stream, pot_out, mx, am);
  hipLaunchKernelGGL(k_inhib, dim3(64), dim3(256), 0, stream, pot_out, mx, am, win, nspv, valv, sv);
  hipLaunchKernelGGL(k_select, dim3(1), dim3(256), 0, stream, win, nspv, valv, winners);
  hipMemsetAsync(d_out, 0, (size_t)122880000 * 4, stream);
  hipLaunchKernelGGL(k_scatter, dim3(64), dim3(256), 0, stream, win, sv, spk_out, pot_out);
}

// Round 2
// 1378.188 us; speedup vs baseline: 1.8746x; 1.8746x over previous
//
#include <hip/hip_runtime.h>
#include <cstdint>
#include <cstddef>

#define HW 16384  // 128*128

// ---------------- conv1 + fire(15) + maxpool 2x2 ----------------
// grid (64 tiles, 5 oc-groups, 15 t), block 256 (16x16). Thread = 1 pooled pixel
// (2x2 conv outs) x 6 output channels. Spike tile staged ONCE per 6 oc.
__global__ __launch_bounds__(256) void k_conv1(const float* __restrict__ x,
                                               const float* __restrict__ w1,
                                               uint8_t* __restrict__ spk_pool) {
  const int tile = blockIdx.x, ocg = blockIdx.y, t = blockIdx.z;
  const int oc0 = ocg * 6;
  const int tx = threadIdx.x & 15, ty = threadIdx.x >> 4;
  const int px0 = (tile & 7) << 4, py0 = (tile >> 3) << 4;  // pooled tile origin
  __shared__ float sx[36][38];
  float acc[6][4];
#pragma unroll
  for (int g = 0; g < 6; ++g)
#pragma unroll
    for (int j = 0; j < 4; ++j) acc[g][j] = 0.f;
  const int iy0 = (py0 << 1) - 2, ix0 = (px0 << 1) - 2;  // input origin (pad=2)
  for (int ic = 0; ic < 6; ++ic) {
    const float* xp = x + ((size_t)(t * 6 + ic) << 16);
    for (int i = threadIdx.x; i < 36 * 36; i += 256) {
      int r = i / 36, c = i - r * 36;
      int gy = iy0 + r, gx = ix0 + c;
      float v = 0.f;
      if ((unsigned)gy < 256u && (unsigned)gx < 256u) v = xp[(gy << 8) + gx];
      sx[r][c] = v;
    }
    __syncthreads();
    float win_[6][6];
#pragma unroll
    for (int r = 0; r < 6; ++r) {
      float2 a = *(const float2*)&sx[2 * ty + r][2 * tx];
      float2 b = *(const float2*)&sx[2 * ty + r][2 * tx + 2];
      float2 c = *(const float2*)&sx[2 * ty + r][2 * tx + 4];
      win_[r][0] = a.x; win_[r][1] = a.y; win_[r][2] = b.x;
      win_[r][3] = b.y; win_[r][4] = c.x; win_[r][5] = c.y;
    }
#pragma unroll
    for (int g = 0; g < 6; ++g) {
      const float* wp = w1 + ((size_t)(oc0 + g) * 6 + ic) * 25;
#pragma unroll
      for (int ky = 0; ky < 5; ++ky)
#pragma unroll
        for (int kx = 0; kx < 5; ++kx) {
          float w = wp[ky * 5 + kx];  // block-uniform -> scalar load
          acc[g][0] += w * win_[ky][kx];
          acc[g][1] += w * win_[ky][kx + 1];
          acc[g][2] += w * win_[ky + 1][kx];
          acc[g][3] += w * win_[ky + 1][kx + 1];
        }
    }
    __syncthreads();
  }
#pragma unroll
  for (int g = 0; g < 6; ++g) {
    int spike = (acc[g][0] > 15.f) || (acc[g][1] > 15.f) ||
                (acc[g][2] > 15.f) || (acc[g][3] > 15.f);
    spk_pool[((size_t)(t * 30 + oc0 + g) << 14) + ((size_t)(py0 + ty) << 7) + (px0 + tx)] =
        (uint8_t)spike;
  }
}

// ---------------- conv2 (pad=1) + fire(10) -> pot2 ----------------
// grid (16 tiles, 25 oc-groups, 15 t), block 256 (16x16). Thread = 2x2 outputs
// x 10 oc (40 accumulators). 34x34 spike tile staged ONCE per 10 oc.
__global__ __launch_bounds__(256) void k_conv2(const uint8_t* __restrict__ spk_pool,
                                               const float* __restrict__ w2,
                                               float* __restrict__ pot2) {
  const int tile = blockIdx.x, ocg = blockIdx.y, t = blockIdx.z;
  const int oc0 = ocg * 10;
  const int bx = (tile & 3) << 5, by = (tile >> 2) << 5;
  const int tx = threadIdx.x & 15, ty = threadIdx.x >> 4;
  __shared__ float sS[34][40];  // stride 40: row bank-offset 8 -> worst 2-way (free)
  float acc[10][4];
#pragma unroll
  for (int g = 0; g < 10; ++g)
#pragma unroll
    for (int j = 0; j < 4; ++j) acc[g][j] = 0.f;
  for (int ic = 0; ic < 30; ++ic) {
    const uint8_t* spc = spk_pool + ((size_t)(t * 30 + ic) << 14);
    for (int i = threadIdx.x; i < 34 * 34; i += 256) {
      int r = i / 34, c = i - r * 34;
      int gy = by - 1 + r, gx = bx - 1 + c;
      float v = 0.f;
      if ((unsigned)gy < 128u && (unsigned)gx < 128u) v = (float)spc[(gy << 7) + gx];
      sS[r][c] = v;
    }
    __syncthreads();
    float win_[4][4];
#pragma unroll
    for (int r = 0; r < 4; ++r) {
      float2 a = *(const float2*)&sS[2 * ty + r][2 * tx];
      float2 b = *(const float2*)&sS[2 * ty + r][2 * tx + 2];
      win_[r][0] = a.x; win_[r][1] = a.y; win_[r][2] = b.x; win_[r][3] = b.y;
    }
#pragma unroll
    for (int g = 0; g < 10; ++g) {
      const float* wp = w2 + ((size_t)(oc0 + g) * 30 + ic) * 9;
#pragma unroll
      for (int kr = 0; kr < 3; ++kr)
#pragma unroll
        for (int ks = 0; ks < 3; ++ks) {
          float w = wp[kr * 3 + ks];  // block-uniform -> scalar load
          acc[g][0] += w * win_[kr][ks];
          acc[g][1] += w * win_[kr][ks + 1];
          acc[g][2] += w * win_[kr + 1][ks];
          acc[g][3] += w * win_[kr + 1][ks + 1];
        }
    }
    __syncthreads();
  }
#pragma unroll
  for (int g = 0; g < 10; ++g) {
    float* outp = pot2 + ((size_t)(t * 250 + oc0 + g) << 14);
    const int gy = by + 2 * ty, gx = bx + 2 * tx;
    float2 v0, v1;
    v0.x = acc[g][0] > 10.f ? acc[g][0] : 0.f;
    v0.y = acc[g][1] > 10.f ? acc[g][1] : 0.f;
    v1.x = acc[g][2] > 10.f ? acc[g][2] : 0.f;
    v1.y = acc[g][3] > 10.f ? acc[g][3] : 0.f;
    *(float2*)&outp[((size_t)gy << 7) + gx] = v0;
    *(float2*)&outp[((size_t)(gy + 1) << 7) + gx] = v1;
  }
}

// ---------------- per-(t,loc) channel max + argmax (first occurrence) ----------------
__global__ __launch_bounds__(256) void k_chanmax(const float* __restrict__ pot2,
                                                 float* __restrict__ mx,
                                                 int* __restrict__ am) {
  const int t = blockIdx.y;
  const int loc = (blockIdx.x << 8) + threadIdx.x;
  const float* p = pot2 + ((size_t)(t * 250) << 14) + loc;
  float best = p[0];
  int bi = 0;
#pragma unroll 5
  for (int c = 1; c < 250; ++c) {
    float v = p[(size_t)c << 14];
    if (v > best) { best = v; bi = c; }
  }
  mx[t * HW + loc] = best;
  am[t * HW + loc] = bi;
}

// ---------------- inhibition combine per location ----------------
__global__ __launch_bounds__(256) void k_inhib(const float* __restrict__ pot2,
                                               const float* __restrict__ mx,
                                               const int* __restrict__ am,
                                               int* __restrict__ win,
                                               float* __restrict__ nspv,
                                               float* __restrict__ valv,
                                               float* __restrict__ sv) {
  const int loc = (blockIdx.x << 8) + threadIdx.x;
  int cnt = 0;
#pragma unroll
  for (int t = 0; t < 15; ++t) cnt += (mx[t * HW + loc] > 0.f) ? 1 : 0;
  const int spiked = (mx[14 * HW + loc] > 0.f) ? 1 : 0;
  int ft = 15 - cnt;
  if (ft > 14) ft = 14;
  if (ft < 0) ft = 0;
  const int wc = am[ft * HW + loc];
  int nsp = 0;
#pragma unroll
  for (int t = 0; t < 15; ++t) {
    float v = pot2[((size_t)(t * 250 + wc) << 14) + loc];
    v = spiked ? v : 0.f;
    sv[t * HW + loc] = v;
    nsp += (v > 0.f) ? 1 : 0;
  }
  int ft2 = 15 - nsp;
  if (ft2 > 14) ft2 = 14;
  float value = spiked ? pot2[((size_t)(ft2 * 250 + wc) << 14) + loc] : 0.f;
  win[loc] = spiked ? wc : -1;
  nspv[loc] = (float)nsp;
  valv[loc] = value;
}

// ---------------- scatter winner-channel values into zeroed outputs ----------------
__global__ __launch_bounds__(256) void k_scatter(const int* __restrict__ win,
                                                 const float* __restrict__ sv,
                                                 float* __restrict__ spk_out,
                                                 float* __restrict__ pot_out) {
  const int loc = (blockIdx.x << 8) + threadIdx.x;
  const int wc = win[loc];
  if (wc < 0) return;
#pragma unroll
  for (int t = 0; t < 15; ++t) {
    float v = sv[t * HW + loc];
    size_t idx = ((size_t)(t * 250 + wc) << 14) + loc;
    pot_out[idx] = v;
    spk_out[idx] = (v > 0.f) ? 1.f : 0.f;
  }
}

// ---------------- k-winner selection (single block) ----------------
__global__ __launch_bounds__(256) void k_select(const int* __restrict__ win,
                                                const float* __restrict__ nspv,
                                                const float* __restrict__ valv,
                                                float* __restrict__ winners) {
  __shared__ float tot[HW];
  __shared__ int wchan[HW];
  __shared__ float redV[256];
  __shared__ int redK[256];
  __shared__ float bcValid[1];
  __shared__ int bcKey[1];
  const int tid = threadIdx.x;

  float lmax = 0.f;
  for (int i = tid; i < HW; i += 256) {
    wchan[i] = win[i];
    lmax = fmaxf(lmax, valv[i]);
  }
  redV[tid] = lmax;
  __syncthreads();
  for (int s = 128; s > 0; s >>= 1) {
    if (tid < s) redV[tid] = fmaxf(redV[tid], redV[tid + s]);
    __syncthreads();
  }
  const float v15 = redV[0] * 15.f;
  __syncthreads();
  for (int i = tid; i < HW; i += 256) tot[i] = nspv[i] * (valv[i] + v15);
  __syncthreads();

  for (int k = 0; k < 8; ++k) {
    float bv = -1.f;
    int bkey = 0x7fffffff;
    for (int i = tid; i < HW; i += 256) {
      float v = tot[i];
      int key = (wchan[i] << 14) + i;
      if (v > bv || (v == bv && key < bkey)) { bv = v; bkey = key; }
    }
    redV[tid] = bv;
    redK[tid] = bkey;
    __syncthreads();
    for (int s = 128; s > 0; s >>= 1) {
      if (tid < s) {
        float ov = redV[tid + s];
        int ok = redK[tid + s];
        if (ov > redV[tid] || (ov == redV[tid] && ok < redK[tid])) {
          redV[tid] = ov;
          redK[tid] = ok;
        }
      }
      __syncthreads();
    }
    if (tid == 0) {
      float mv = redV[0];
      int mk = redK[0];
      int valid = (mv != 0.f) ? 1 : 0;
      int c = mk >> 14, l = mk & (HW - 1);
      winners[k * 3 + 0] = valid ? (float)c : -1.f;
      winners[k * 3 + 1] = valid ? (float)(l >> 7) : -1.f;
      winners[k * 3 + 2] = valid ? (float)(l & 127) : -1.f;
      bcValid[0] = valid ? 1.f : 0.f;
      bcKey[0] = mk;
    }
    __syncthreads();
    if (bcValid[0] > 0.f) {
      int mk = bcKey[0];
      int c = mk >> 14, h = (mk & (HW - 1)) >> 7, w = mk & 127;
      for (int i = tid; i < HW; i += 256) {
        int hh = i >> 7, ww = i & 127;
        int dh = hh - h; if (dh < 0) dh = -dh;
        int dw = ww - w; if (dw < 0) dw = -dw;
        bool m = (wchan[i] == c) || (dh <= 1 && dw <= 1);
        if (m) tot[i] = 0.f;
      }
    }
    __syncthreads();
  }
}

extern "C" void kernel_launch(void* const* d_in, const int* in_sizes, int n_in,
                              void* d_out, int out_size, void* d_ws, size_t ws_size,
                              hipStream_t stream) {
  const float* x = (const float*)d_in[0];
  const float* w1 = (const float*)d_in[1];
  const float* w2 = (const float*)d_in[2];
  (void)in_sizes; (void)n_in; (void)out_size; (void)ws_size;

  float* spk_out = (float*)d_out;
  float* pot_out = spk_out + 61440000;  // pot2 scratch == final pot at winner ch
  float* winners = spk_out + 122880000;

  uint8_t* ws = (uint8_t*)d_ws;
  uint8_t* spk_pool = ws;                // 7,372,800 B  u8 [15][30][128][128]
  float* mx = (float*)(ws + 7372800);    //   983,040 B  [15][16384]
  int* am = (int*)(ws + 8355840);        //   983,040 B
  int* win = (int*)(ws + 9338880);       //    65,536 B
  float* nspv = (float*)(ws + 9404416);  //    65,536 B
  float* valv = (float*)(ws + 9469952);  //    65,536 B
  float* sv = (float*)(ws + 9535488);    //   983,040 B  [15][16384]

  hipLaunchKernelGGL(k_conv1, dim3(64, 5, 15), dim3(256), 0, stream, x, w1, spk_pool);
  hipLaunchKernelGGL(k_conv2, dim3(16, 25, 15), dim3(256), 0, stream, spk_pool, w2, pot_out);
  hipLaunchKernelGGL(k_chanmax, dim3(64, 15), dim3(256), 0, stream, pot_out, mx, am);
  hipLaunchKernelGGL(k_inhib, dim3(64), dim3(256), 0, stream, pot_out, mx, am, win, nspv, valv, sv);
  hipLaunchKernelGGL(k_select, dim3(1), dim3(256), 0, stream, win, nspv, valv, winners);
  hipMemsetAsync(d_out, 0, (size_t)122880000 * 4, stream);
  hipLaunchKernelGGL(k_scatter, dim3(64), dim3(256), 0, stream, win, sv, spk_out, pot_out);
}

// Round 3
// 1323.559 us; speedup vs baseline: 1.9520x; 1.0413x over previous
//
#include <hip/hip_runtime.h>
#include <cstdint>
#include <cstddef>

#define HW 16384  // 128*128

// ---------------- conv1 + fire(15) + maxpool 2x2 ----------------
// grid (64 tiles, 5 oc-groups, 15 t), block 256 (16x16). Thread = 1 pooled pixel
// (2x2 conv outs) x 6 oc. Staging offsets hoisted; ic+1 prefetched in regs.
__global__ __launch_bounds__(256) void k_conv1(const float* __restrict__ x,
                                               const float* __restrict__ w1,
                                               uint8_t* __restrict__ spk_pool) {
  const int tile = blockIdx.x, ocg = blockIdx.y, t = blockIdx.z;
  const int oc0 = ocg * 6;
  const int tid = threadIdx.x;
  const int tx = tid & 15, ty = tid >> 4;
  const int px0 = (tile & 7) << 4, py0 = (tile >> 3) << 4;
  __shared__ float sx[36 * 38];
  const int iy0 = (py0 << 1) - 2, ix0 = (px0 << 1) - 2;  // pad=2

  // hoisted staging coords (36x36 = 1296 elems, 6 slots)
  int goff[6], soff[6];
  bool act[6];
#pragma unroll
  for (int j = 0; j < 6; ++j) {
    int idx = tid + 256 * j;
    bool a = idx < 1296;
    int r = idx / 36, c = idx - r * 36;
    int gy = iy0 + r, gx = ix0 + c;
    bool inb = a && (unsigned)gy < 256u && (unsigned)gx < 256u;
    goff[j] = inb ? ((gy << 8) + gx) : 0;
    soff[j] = a ? (r * 38 + c) : 0;
    act[j] = a;
    if (!inb) goff[j] = -1;
  }

  float acc[6][4];
#pragma unroll
  for (int g = 0; g < 6; ++g)
#pragma unroll
    for (int j = 0; j < 4; ++j) acc[g][j] = 0.f;

  float v[6];
  {
    const float* xp = x + ((size_t)(t * 6) << 16);
#pragma unroll
    for (int j = 0; j < 6; ++j) v[j] = (goff[j] >= 0) ? xp[goff[j]] : 0.f;
#pragma unroll
    for (int j = 0; j < 6; ++j)
      if (act[j]) sx[soff[j]] = v[j];
  }
  __syncthreads();

  for (int ic = 0; ic < 6; ++ic) {
    if (ic < 5) {
      const float* xp = x + ((size_t)(t * 6 + ic + 1) << 16);
#pragma unroll
      for (int j = 0; j < 6; ++j) v[j] = (goff[j] >= 0) ? xp[goff[j]] : 0.f;
    }
    float win_[6][6];
#pragma unroll
    for (int r = 0; r < 6; ++r) {
      float2 a = *(const float2*)&sx[(2 * ty + r) * 38 + 2 * tx];
      float2 b = *(const float2*)&sx[(2 * ty + r) * 38 + 2 * tx + 2];
      float2 c = *(const float2*)&sx[(2 * ty + r) * 38 + 2 * tx + 4];
      win_[r][0] = a.x; win_[r][1] = a.y; win_[r][2] = b.x;
      win_[r][3] = b.y; win_[r][4] = c.x; win_[r][5] = c.y;
    }
#pragma unroll
    for (int g = 0; g < 6; ++g) {
      const float* wp = w1 + ((size_t)(oc0 + g) * 6 + ic) * 25;
#pragma unroll
      for (int ky = 0; ky < 5; ++ky)
#pragma unroll
        for (int kx = 0; kx < 5; ++kx) {
          float w = wp[ky * 5 + kx];  // block-uniform -> SGPR
          acc[g][0] += w * win_[ky][kx];
          acc[g][1] += w * win_[ky][kx + 1];
          acc[g][2] += w * win_[ky + 1][kx];
          acc[g][3] += w * win_[ky + 1][kx + 1];
        }
    }
    __syncthreads();
    if (ic < 5) {
#pragma unroll
      for (int j = 0; j < 6; ++j)
        if (act[j]) sx[soff[j]] = v[j];
    }
    __syncthreads();
  }
#pragma unroll
  for (int g = 0; g < 6; ++g) {
    int spike = (acc[g][0] > 15.f) || (acc[g][1] > 15.f) ||
                (acc[g][2] > 15.f) || (acc[g][3] > 15.f);
    spk_pool[((size_t)(t * 30 + oc0 + g) << 14) + ((size_t)(py0 + ty) << 7) + (px0 + tx)] =
        (uint8_t)spike;
  }
}

// ---------------- conv2 (pad=1) + fire(10) -> pot2, fused channel-max atomics -----------
// grid (16 tiles, 25 oc-groups, 15 t), block 256 (16x16). Thread = 2x2 outputs x 10 oc.
__global__ __launch_bounds__(256) void k_conv2(const uint8_t* __restrict__ spk_pool,
                                               const float* __restrict__ w2,
                                               float* __restrict__ pot2,
                                               unsigned long long* __restrict__ mp) {
  const int tile = blockIdx.x, ocg = blockIdx.y, t = blockIdx.z;
  const int oc0 = ocg * 10;
  const int tid = threadIdx.x;
  const int bx = (tile & 3) << 5, by = (tile >> 2) << 5;
  const int tx = tid & 15, ty = tid >> 4;
  __shared__ float sS[34 * 40];  // row stride 40

  // hoisted staging coords (34x34 = 1156 elems, 5 slots)
  int goff[5], soff[5];
  bool act[5];
#pragma unroll
  for (int j = 0; j < 5; ++j) {
    int idx = tid + 256 * j;
    bool a = idx < 1156;
    int r = idx / 34, c = idx - r * 34;
    int gy = by - 1 + r, gx = bx - 1 + c;
    bool inb = a && (unsigned)gy < 128u && (unsigned)gx < 128u;
    goff[j] = inb ? ((gy << 7) + gx) : -1;
    soff[j] = a ? (r * 40 + c) : 0;
    act[j] = a;
  }

  float acc[10][4];
#pragma unroll
  for (int g = 0; g < 10; ++g)
#pragma unroll
    for (int j = 0; j < 4; ++j) acc[g][j] = 0.f;

  float v[5];
  {
    const uint8_t* spc = spk_pool + ((size_t)(t * 30) << 14);
#pragma unroll
    for (int j = 0; j < 5; ++j) v[j] = (goff[j] >= 0) ? (float)spc[goff[j]] : 0.f;
#pragma unroll
    for (int j = 0; j < 5; ++j)
      if (act[j]) sS[soff[j]] = v[j];
  }
  __syncthreads();

  for (int ic = 0; ic < 30; ++ic) {
    if (ic < 29) {
      const uint8_t* spc = spk_pool + ((size_t)(t * 30 + ic + 1) << 14);
#pragma unroll
      for (int j = 0; j < 5; ++j) v[j] = (goff[j] >= 0) ? (float)spc[goff[j]] : 0.f;
    }
    float win_[4][4];
#pragma unroll
    for (int r = 0; r < 4; ++r) {
      float2 a = *(const float2*)&sS[(2 * ty + r) * 40 + 2 * tx];
      float2 b = *(const float2*)&sS[(2 * ty + r) * 40 + 2 * tx + 2];
      win_[r][0] = a.x; win_[r][1] = a.y; win_[r][2] = b.x; win_[r][3] = b.y;
    }
#pragma unroll
    for (int g = 0; g < 10; ++g) {
      const float* wp = w2 + ((size_t)(oc0 + g) * 30 + ic) * 9;
#pragma unroll
      for (int kr = 0; kr < 3; ++kr)
#pragma unroll
        for (int ks = 0; ks < 3; ++ks) {
          float w = wp[kr * 3 + ks];  // block-uniform -> SGPR
          acc[g][0] += w * win_[kr][ks];
          acc[g][1] += w * win_[kr][ks + 1];
          acc[g][2] += w * win_[kr + 1][ks];
          acc[g][3] += w * win_[kr + 1][ks + 1];
        }
    }
    __syncthreads();
    if (ic < 29) {
#pragma unroll
      for (int j = 0; j < 5; ++j)
        if (act[j]) sS[soff[j]] = v[j];
    }
    __syncthreads();
  }

  // fire + write pot2 + per-loc max/argmax over this block's 10 oc
  const int gy = by + 2 * ty, gx = bx + 2 * tx;
  float mxv[4] = {0.f, 0.f, 0.f, 0.f};
  int mxc[4] = {0, 0, 0, 0};
#pragma unroll
  for (int g = 0; g < 10; ++g) {
    float* outp = pot2 + ((size_t)(t * 250 + oc0 + g) << 14);
    float2 v0, v1;
    v0.x = acc[g][0] > 10.f ? acc[g][0] : 0.f;
    v0.y = acc[g][1] > 10.f ? acc[g][1] : 0.f;
    v1.x = acc[g][2] > 10.f ? acc[g][2] : 0.f;
    v1.y = acc[g][3] > 10.f ? acc[g][3] : 0.f;
    *(float2*)&outp[((size_t)gy << 7) + gx] = v0;
    *(float2*)&outp[((size_t)(gy + 1) << 7) + gx] = v1;
    if (v0.x > mxv[0]) { mxv[0] = v0.x; mxc[0] = g; }
    if (v0.y > mxv[1]) { mxv[1] = v0.y; mxc[1] = g; }
    if (v1.x > mxv[2]) { mxv[2] = v1.x; mxc[2] = g; }
    if (v1.y > mxv[3]) { mxv[3] = v1.y; mxc[3] = g; }
  }
  unsigned long long* mpt = mp + (size_t)t * HW;
  const int locs[4] = {(gy << 7) + gx, (gy << 7) + gx + 1,
                       ((gy + 1) << 7) + gx, ((gy + 1) << 7) + gx + 1};
#pragma unroll
  for (int j = 0; j < 4; ++j) {
    unsigned long long pk =
        ((unsigned long long)__float_as_uint(mxv[j]) << 32) |
        (unsigned long long)(1023 - (oc0 + mxc[j]));
    atomicMax(&mpt[locs[j]], pk);
  }
}

// ---------------- inhibition combine per location ----------------
__global__ __launch_bounds__(256) void k_inhib(const float* __restrict__ pot2,
                                               const unsigned long long* __restrict__ mp,
                                               int* __restrict__ win,
                                               float* __restrict__ nspv,
                                               float* __restrict__ valv,
                                               float* __restrict__ sv) {
  const int loc = (blockIdx.x << 8) + threadIdx.x;
  int cnt = 0;
  float last = 0.f;
  unsigned long long pks[15];
#pragma unroll
  for (int t = 0; t < 15; ++t) {
    pks[t] = mp[t * HW + loc];
    float v = __uint_as_float((unsigned)(pks[t] >> 32));
    cnt += (v > 0.f) ? 1 : 0;
    if (t == 14) last = v;
  }
  const int spiked = (last > 0.f) ? 1 : 0;
  int ft = 15 - cnt;
  if (ft > 14) ft = 14;
  if (ft < 0) ft = 0;
  const int wc = 1023 - (int)(pks[ft] & 1023ULL);
  int nsp = 0;
#pragma unroll
  for (int t = 0; t < 15; ++t) {
    float v = pot2[((size_t)(t * 250 + wc) << 14) + loc];
    v = spiked ? v : 0.f;
    sv[t * HW + loc] = v;
    nsp += (v > 0.f) ? 1 : 0;
  }
  int ft2 = 15 - nsp;
  if (ft2 > 14) ft2 = 14;
  float value = spiked ? pot2[((size_t)(ft2 * 250 + wc) << 14) + loc] : 0.f;
  win[loc] = spiked ? wc : -1;
  nspv[loc] = (float)nsp;
  valv[loc] = value;
}

// ---------------- scatter winner-channel values into zeroed outputs ----------------
__global__ __launch_bounds__(256) void k_scatter(const int* __restrict__ win,
                                                 const float* __restrict__ sv,
                                                 float* __restrict__ spk_out,
                                                 float* __restrict__ pot_out) {
  const int loc = (blockIdx.x << 8) + threadIdx.x;
  const int wc = win[loc];
  if (wc < 0) return;
#pragma unroll
  for (int t = 0; t < 15; ++t) {
    float v = sv[t * HW + loc];
    size_t idx = ((size_t)(t * 250 + wc) << 14) + loc;
    pot_out[idx] = v;
    spk_out[idx] = (v > 0.f) ? 1.f : 0.f;
  }
}

// ---------------- k-winner selection (single block) ----------------
__global__ __launch_bounds__(256) void k_select(const int* __restrict__ win,
                                                const float* __restrict__ nspv,
                                                const float* __restrict__ valv,
                                                float* __restrict__ winners) {
  __shared__ float tot[HW];
  __shared__ int wchan[HW];
  __shared__ float redV[256];
  __shared__ int redK[256];
  __shared__ float bcValid[1];
  __shared__ int bcKey[1];
  const int tid = threadIdx.x;

  float lmax = 0.f;
  for (int i = tid; i < HW; i += 256) {
    wchan[i] = win[i];
    lmax = fmaxf(lmax, valv[i]);
  }
  redV[tid] = lmax;
  __syncthreads();
  for (int s = 128; s > 0; s >>= 1) {
    if (tid < s) redV[tid] = fmaxf(redV[tid], redV[tid + s]);
    __syncthreads();
  }
  const float v15 = redV[0] * 15.f;
  __syncthreads();
  for (int i = tid; i < HW; i += 256) tot[i] = nspv[i] * (valv[i] + v15);
  __syncthreads();

  for (int k = 0; k < 8; ++k) {
    float bv = -1.f;
    int bkey = 0x7fffffff;
    for (int i = tid; i < HW; i += 256) {
      float v = tot[i];
      int key = (wchan[i] << 14) + i;
      if (v > bv || (v == bv && key < bkey)) { bv = v; bkey = key; }
    }
    redV[tid] = bv;
    redK[tid] = bkey;
    __syncthreads();
    for (int s = 128; s > 0; s >>= 1) {
      if (tid < s) {
        float ov = redV[tid + s];
        int ok = redK[tid + s];
        if (ov > redV[tid] || (ov == redV[tid] && ok < redK[tid])) {
          redV[tid] = ov;
          redK[tid] = ok;
        }
      }
      __syncthreads();
    }
    if (tid == 0) {
      float mv = redV[0];
      int mk = redK[0];
      int valid = (mv != 0.f) ? 1 : 0;
      int c = mk >> 14, l = mk & (HW - 1);
      winners[k * 3 + 0] = valid ? (float)c : -1.f;
      winners[k * 3 + 1] = valid ? (float)(l >> 7) : -1.f;
      winners[k * 3 + 2] = valid ? (float)(l & 127) : -1.f;
      bcValid[0] = valid ? 1.f : 0.f;
      bcKey[0] = mk;
    }
    __syncthreads();
    if (bcValid[0] > 0.f) {
      int mk = bcKey[0];
      int c = mk >> 14, h = (mk & (HW - 1)) >> 7, w = mk & 127;
      for (int i = tid; i < HW; i += 256) {
        int hh = i >> 7, ww = i & 127;
        int dh = hh - h; if (dh < 0) dh = -dh;
        int dw = ww - w; if (dw < 0) dw = -dw;
        bool m = (wchan[i] == c) || (dh <= 1 && dw <= 1);
        if (m) tot[i] = 0.f;
      }
    }
    __syncthreads();
  }
}

extern "C" void kernel_launch(void* const* d_in, const int* in_sizes, int n_in,
                              void* d_out, int out_size, void* d_ws, size_t ws_size,
                              hipStream_t stream) {
  const float* x = (const float*)d_in[0];
  const float* w1 = (const float*)d_in[1];
  const float* w2 = (const float*)d_in[2];
  (void)in_sizes; (void)n_in; (void)out_size; (void)ws_size;

  float* spk_out = (float*)d_out;
  float* pot_out = spk_out + 61440000;  // pot2 scratch == final pot at winner ch
  float* winners = spk_out + 122880000;

  uint8_t* ws = (uint8_t*)d_ws;
  uint8_t* spk_pool = ws;                                  // 7,372,800 B u8
  unsigned long long* mp = (unsigned long long*)(ws + 7372800);  // 1,966,080 B u64 [15][HW]
  int* win = (int*)(ws + 9338880);       //  65,536 B
  float* nspv = (float*)(ws + 9404416);  //  65,536 B
  float* valv = (float*)(ws + 9469952);  //  65,536 B
  float* sv = (float*)(ws + 9535488);    // 983,040 B  [15][16384]

  hipMemsetAsync(mp, 0, (size_t)15 * HW * 8, stream);
  hipLaunchKernelGGL(k_conv1, dim3(64, 5, 15), dim3(256), 0, stream, x, w1, spk_pool);
  hipLaunchKernelGGL(k_conv2, dim3(16, 25, 15), dim3(256), 0, stream, spk_pool, w2, pot_out, mp);
  hipLaunchKernelGGL(k_inhib, dim3(64), dim3(256), 0, stream, pot_out, mp, win, nspv, valv, sv);
  hipLaunchKernelGGL(k_select, dim3(1), dim3(256), 0, stream, win, nspv, valv, winners);
  hipMemsetAsync(d_out, 0, (size_t)122880000 * 4, stream);
  hipLaunchKernelGGL(k_scatter, dim3(64), dim3(256), 0, stream, win, sv, spk_out, pot_out);
}

// Round 4
// 1217.399 us; speedup vs baseline: 2.1222x; 1.0872x over previous
//
#include <hip/hip_runtime.h>
#include <cstdint>
#include <cstddef>

#define HW 16384  // 128*128

// ---------------- conv1 + fire(15) + maxpool 2x2 ----------------
// grid (64 tiles, 5 oc-groups, 15 t), block 256 (16x16). Thread = 1 pooled pixel
// (2x2 conv outs) x 6 oc. LDS double-buffered, 1 barrier/ic, VGPR budget 128.
__global__ __launch_bounds__(256, 4) void k_conv1(const float* __restrict__ x,
                                                  const float* __restrict__ w1,
                                                  uint8_t* __restrict__ spk_pool) {
  const int tile = blockIdx.x, ocg = blockIdx.y, t = blockIdx.z;
  const int oc0 = ocg * 6;
  const int tid = threadIdx.x;
  const int tx = tid & 15, ty = tid >> 4;
  const int px0 = (tile & 7) << 4, py0 = (tile >> 3) << 4;
  __shared__ float sx[2][36 * 38];
  const int iy0 = (py0 << 1) - 2, ix0 = (px0 << 1) - 2;  // pad=2

  int goff[6], soff[6];
  bool act[6];
#pragma unroll
  for (int j = 0; j < 6; ++j) {
    int idx = tid + 256 * j;
    bool a = idx < 1296;
    int r = idx / 36, c = idx - r * 36;
    int gy = iy0 + r, gx = ix0 + c;
    bool inb = a && (unsigned)gy < 256u && (unsigned)gx < 256u;
    goff[j] = inb ? ((gy << 8) + gx) : -1;
    soff[j] = a ? (r * 38 + c) : 0;
    act[j] = a;
  }

  float acc[6][4];
#pragma unroll
  for (int g = 0; g < 6; ++g)
#pragma unroll
    for (int j = 0; j < 4; ++j) acc[g][j] = 0.f;

  const float* xt = x + ((size_t)(t * 6) << 16);
  float v[6];
#pragma unroll
  for (int j = 0; j < 6; ++j) v[j] = (goff[j] >= 0) ? xt[goff[j]] : 0.f;
#pragma unroll
  for (int j = 0; j < 6; ++j)
    if (act[j]) sx[0][soff[j]] = v[j];
  __syncthreads();

  for (int ic = 0; ic < 6; ++ic) {
    const int cur = ic & 1, nxt = cur ^ 1;
    if (ic < 5) {
      const float* xp = xt + ((size_t)(ic + 1) << 16);
#pragma unroll
      for (int j = 0; j < 6; ++j) v[j] = (goff[j] >= 0) ? xp[goff[j]] : 0.f;
    }
    float win_[6][6];
#pragma unroll
    for (int r = 0; r < 6; ++r) {
      float2 a = *(const float2*)&sx[cur][(2 * ty + r) * 38 + 2 * tx];
      float2 b = *(const float2*)&sx[cur][(2 * ty + r) * 38 + 2 * tx + 2];
      float2 c = *(const float2*)&sx[cur][(2 * ty + r) * 38 + 2 * tx + 4];
      win_[r][0] = a.x; win_[r][1] = a.y; win_[r][2] = b.x;
      win_[r][3] = b.y; win_[r][4] = c.x; win_[r][5] = c.y;
    }
#pragma unroll
    for (int g = 0; g < 6; ++g) {
      const float* wp = w1 + ((size_t)(oc0 + g) * 6 + ic) * 25;
#pragma unroll
      for (int ky = 0; ky < 5; ++ky)
#pragma unroll
        for (int kx = 0; kx < 5; ++kx) {
          float w = wp[ky * 5 + kx];  // block-uniform -> SGPR
          acc[g][0] += w * win_[ky][kx];
          acc[g][1] += w * win_[ky][kx + 1];
          acc[g][2] += w * win_[ky + 1][kx];
          acc[g][3] += w * win_[ky + 1][kx + 1];
        }
    }
    if (ic < 5) {
#pragma unroll
      for (int j = 0; j < 6; ++j)
        if (act[j]) sx[nxt][soff[j]] = v[j];
    }
    __syncthreads();
  }
#pragma unroll
  for (int g = 0; g < 6; ++g) {
    int spike = (acc[g][0] > 15.f) || (acc[g][1] > 15.f) ||
                (acc[g][2] > 15.f) || (acc[g][3] > 15.f);
    spk_pool[((size_t)(t * 30 + oc0 + g) << 14) + ((size_t)(py0 + ty) << 7) + (px0 + tx)] =
        (uint8_t)spike;
  }
}

// ---------------- conv2 (pad=1) + fire(10) -> pot2, fused channel-max atomics -----------
// grid (16 tiles, 25 oc-groups, 15 t), block 256. Thread = 2x2 outputs x 10 oc.
// LDS double-buffered (1 barrier/ic), zero-tile skip flag, VGPR budget 128.
__global__ __launch_bounds__(256, 4) void k_conv2(const uint8_t* __restrict__ spk_pool,
                                                  const float* __restrict__ w2,
                                                  float* __restrict__ pot2,
                                                  unsigned long long* __restrict__ mp) {
  const int tile = blockIdx.x, ocg = blockIdx.y, t = blockIdx.z;
  const int oc0 = ocg * 10;
  const int tid = threadIdx.x;
  const int bx = (tile & 3) << 5, by = (tile >> 2) << 5;
  const int tx = tid & 15, ty = tid >> 4;
  __shared__ float sS[2][34 * 40];
  __shared__ int sFlag[2][4];

  int goff[5], soff[5];
  bool act[5];
#pragma unroll
  for (int j = 0; j < 5; ++j) {
    int idx = tid + 256 * j;
    bool a = idx < 1156;
    int r = idx / 34, c = idx - r * 34;
    int gy = by - 1 + r, gx = bx - 1 + c;
    bool inb = a && (unsigned)gy < 128u && (unsigned)gx < 128u;
    goff[j] = inb ? ((gy << 7) + gx) : -1;
    soff[j] = a ? (r * 40 + c) : 0;
    act[j] = a;
  }

  float acc[10][4];
#pragma unroll
  for (int g = 0; g < 10; ++g)
#pragma unroll
    for (int j = 0; j < 4; ++j) acc[g][j] = 0.f;

  const uint8_t* spk_t = spk_pool + ((size_t)(t * 30) << 14);
  float v[5];
#pragma unroll
  for (int j = 0; j < 5; ++j) v[j] = (goff[j] >= 0) ? (float)spk_t[goff[j]] : 0.f;
  {
    bool nz = (v[0] + v[1] + v[2] + v[3] + v[4]) != 0.f;
    bool wnz = __any(nz);
    if ((tid & 63) == 0) sFlag[0][tid >> 6] = wnz ? 1 : 0;
  }
#pragma unroll
  for (int j = 0; j < 5; ++j)
    if (act[j]) sS[0][soff[j]] = v[j];
  __syncthreads();

  for (int ic = 0; ic < 30; ++ic) {
    const int cur = ic & 1, nxt = cur ^ 1;
    if (ic < 29) {
      const uint8_t* spc = spk_t + ((size_t)(ic + 1) << 14);
#pragma unroll
      for (int j = 0; j < 5; ++j) v[j] = (goff[j] >= 0) ? (float)spc[goff[j]] : 0.f;
    }
    const int flag = sFlag[cur][0] | sFlag[cur][1] | sFlag[cur][2] | sFlag[cur][3];
    if (flag) {
      float win_[4][4];
#pragma unroll
      for (int r = 0; r < 4; ++r) {
        float2 a = *(const float2*)&sS[cur][(2 * ty + r) * 40 + 2 * tx];
        float2 b = *(const float2*)&sS[cur][(2 * ty + r) * 40 + 2 * tx + 2];
        win_[r][0] = a.x; win_[r][1] = a.y; win_[r][2] = b.x; win_[r][3] = b.y;
      }
#pragma unroll
      for (int g = 0; g < 10; ++g) {
        const float* wp = w2 + ((size_t)(oc0 + g) * 30 + ic) * 9;
#pragma unroll
        for (int kr = 0; kr < 3; ++kr)
#pragma unroll
          for (int ks = 0; ks < 3; ++ks) {
            float w = wp[kr * 3 + ks];  // block-uniform -> SGPR
            acc[g][0] += w * win_[kr][ks];
            acc[g][1] += w * win_[kr][ks + 1];
            acc[g][2] += w * win_[kr + 1][ks];
            acc[g][3] += w * win_[kr + 1][ks + 1];
          }
      }
    }
    if (ic < 29) {
      bool nz = (v[0] + v[1] + v[2] + v[3] + v[4]) != 0.f;
      bool wnz = __any(nz);
      if ((tid & 63) == 0) sFlag[nxt][tid >> 6] = wnz ? 1 : 0;
#pragma unroll
      for (int j = 0; j < 5; ++j)
        if (act[j]) sS[nxt][soff[j]] = v[j];
    }
    __syncthreads();
  }

  // fire + write pot2 + per-loc max/argmax over this block's 10 oc
  const int gy = by + 2 * ty, gx = bx + 2 * tx;
  float mxv[4] = {0.f, 0.f, 0.f, 0.f};
  int mxc[4] = {0, 0, 0, 0};
#pragma unroll
  for (int g = 0; g < 10; ++g) {
    float* outp = pot2 + ((size_t)(t * 250 + oc0 + g) << 14);
    float2 v0, v1;
    v0.x = acc[g][0] > 10.f ? acc[g][0] : 0.f;
    v0.y = acc[g][1] > 10.f ? acc[g][1] : 0.f;
    v1.x = acc[g][2] > 10.f ? acc[g][2] : 0.f;
    v1.y = acc[g][3] > 10.f ? acc[g][3] : 0.f;
    *(float2*)&outp[((size_t)gy << 7) + gx] = v0;
    *(float2*)&outp[((size_t)(gy + 1) << 7) + gx] = v1;
    if (v0.x > mxv[0]) { mxv[0] = v0.x; mxc[0] = g; }
    if (v0.y > mxv[1]) { mxv[1] = v0.y; mxc[1] = g; }
    if (v1.x > mxv[2]) { mxv[2] = v1.x; mxc[2] = g; }
    if (v1.y > mxv[3]) { mxv[3] = v1.y; mxc[3] = g; }
  }
  unsigned long long* mpt = mp + (size_t)t * HW;
  const int locs[4] = {(gy << 7) + gx, (gy << 7) + gx + 1,
                       ((gy + 1) << 7) + gx, ((gy + 1) << 7) + gx + 1};
#pragma unroll
  for (int j = 0; j < 4; ++j) {
    unsigned long long pk =
        ((unsigned long long)__float_as_uint(mxv[j]) << 32) |
        (unsigned long long)(1023 - (oc0 + mxc[j]));
    atomicMax(&mpt[locs[j]], pk);
  }
}

// ---------------- inhibition combine per location ----------------
// grid 256 blocks x 64 threads
__global__ __launch_bounds__(64) void k_inhib(const float* __restrict__ pot2,
                                              const unsigned long long* __restrict__ mp,
                                              int* __restrict__ win,
                                              float* __restrict__ nspv,
                                              float* __restrict__ valv,
                                              float* __restrict__ sv) {
  const int loc = (blockIdx.x << 6) + threadIdx.x;
  int cnt = 0;
  float last = 0.f;
  unsigned long long pks[15];
#pragma unroll
  for (int t = 0; t < 15; ++t) {
    pks[t] = mp[t * HW + loc];
    float v = __uint_as_float((unsigned)(pks[t] >> 32));
    cnt += (v > 0.f) ? 1 : 0;
    if (t == 14) last = v;
  }
  const int spiked = (last > 0.f) ? 1 : 0;
  int ft = 15 - cnt;
  if (ft > 14) ft = 14;
  if (ft < 0) ft = 0;
  int wc = 1023 - (int)(pks[ft] & 1023ULL);
  if ((unsigned)wc > 249u) wc = 0;
  int nsp = 0;
#pragma unroll
  for (int t = 0; t < 15; ++t) {
    float v = pot2[((size_t)(t * 250 + wc) << 14) + loc];
    v = spiked ? v : 0.f;
    sv[t * HW + loc] = v;
    nsp += (v > 0.f) ? 1 : 0;
  }
  int ft2 = 15 - nsp;
  if (ft2 > 14) ft2 = 14;
  float value = spiked ? pot2[((size_t)(ft2 * 250 + wc) << 14) + loc] : 0.f;
  win[loc] = spiked ? wc : -1;
  nspv[loc] = (float)nsp;
  valv[loc] = value;
}

// ---------------- scatter winner-channel values into zeroed outputs ----------------
__global__ __launch_bounds__(64) void k_scatter(const int* __restrict__ win,
                                                const float* __restrict__ sv,
                                                float* __restrict__ spk_out,
                                                float* __restrict__ pot_out) {
  const int loc = (blockIdx.x << 6) + threadIdx.x;
  const int wc = win[loc];
  if (wc < 0) return;
#pragma unroll
  for (int t = 0; t < 15; ++t) {
    float v = sv[t * HW + loc];
    size_t idx = ((size_t)(t * 250 + wc) << 14) + loc;
    pot_out[idx] = v;
    spk_out[idx] = (v > 0.f) ? 1.f : 0.f;
  }
}

// ---------------- k-winner selection (single block) ----------------
__global__ __launch_bounds__(256) void k_select(const int* __restrict__ win,
                                                const float* __restrict__ nspv,
                                                const float* __restrict__ valv,
                                                float* __restrict__ winners) {
  __shared__ float tot[HW];
  __shared__ int wchan[HW];
  __shared__ float redV[256];
  __shared__ int redK[256];
  __shared__ float bcValid[1];
  __shared__ int bcKey[1];
  const int tid = threadIdx.x;

  float lmax = 0.f;
  for (int i = tid; i < HW; i += 256) {
    wchan[i] = win[i];
    lmax = fmaxf(lmax, valv[i]);
  }
  redV[tid] = lmax;
  __syncthreads();
  for (int s = 128; s > 0; s >>= 1) {
    if (tid < s) redV[tid] = fmaxf(redV[tid], redV[tid + s]);
    __syncthreads();
  }
  const float v15 = redV[0] * 15.f;
  __syncthreads();
  for (int i = tid; i < HW; i += 256) tot[i] = nspv[i] * (valv[i] + v15);
  __syncthreads();

  for (int k = 0; k < 8; ++k) {
    float bv = -1.f;
    int bkey = 0x7fffffff;
    for (int i = tid; i < HW; i += 256) {
      float v = tot[i];
      int key = (wchan[i] << 14) + i;
      if (v > bv || (v == bv && key < bkey)) { bv = v; bkey = key; }
    }
    redV[tid] = bv;
    redK[tid] = bkey;
    __syncthreads();
    for (int s = 128; s > 0; s >>= 1) {
      if (tid < s) {
        float ov = redV[tid + s];
        int ok = redK[tid + s];
        if (ov > redV[tid] || (ov == redV[tid] && ok < redK[tid])) {
          redV[tid] = ov;
          redK[tid] = ok;
        }
      }
      __syncthreads();
    }
    if (tid == 0) {
      float mv = redV[0];
      int mk = redK[0];
      int valid = (mv != 0.f) ? 1 : 0;
      int c = mk >> 14, l = mk & (HW - 1);
      winners[k * 3 + 0] = valid ? (float)c : -1.f;
      winners[k * 3 + 1] = valid ? (float)(l >> 7) : -1.f;
      winners[k * 3 + 2] = valid ? (float)(l & 127) : -1.f;
      bcValid[0] = valid ? 1.f : 0.f;
      bcKey[0] = mk;
    }
    __syncthreads();
    if (bcValid[0] > 0.f) {
      int mk = bcKey[0];
      int c = mk >> 14, h = (mk & (HW - 1)) >> 7, w = mk & 127;
      for (int i = tid; i < HW; i += 256) {
        int hh = i >> 7, ww = i & 127;
        int dh = hh - h; if (dh < 0) dh = -dh;
        int dw = ww - w; if (dw < 0) dw = -dw;
        bool m = (wchan[i] == c) || (dh <= 1 && dw <= 1);
        if (m) tot[i] = 0.f;
      }
    }
    __syncthreads();
  }
}

extern "C" void kernel_launch(void* const* d_in, const int* in_sizes, int n_in,
                              void* d_out, int out_size, void* d_ws, size_t ws_size,
                              hipStream_t stream) {
  const float* x = (const float*)d_in[0];
  const float* w1 = (const float*)d_in[1];
  const float* w2 = (const float*)d_in[2];
  (void)in_sizes; (void)n_in; (void)out_size; (void)ws_size;

  float* spk_out = (float*)d_out;
  float* pot_out = spk_out + 61440000;  // pot2 scratch == final pot at winner ch
  float* winners = spk_out + 122880000;

  uint8_t* ws = (uint8_t*)d_ws;
  uint8_t* spk_pool = ws;                                        // 7,372,800 B u8
  unsigned long long* mp = (unsigned long long*)(ws + 7372800);  // 1,966,080 B u64 [15][HW]
  int* win = (int*)(ws + 9338880);       //  65,536 B
  float* nspv = (float*)(ws + 9404416);  //  65,536 B
  float* valv = (float*)(ws + 9469952);  //  65,536 B
  float* sv = (float*)(ws + 9535488);    // 983,040 B  [15][16384]

  hipMemsetAsync(mp, 0, (size_t)15 * HW * 8, stream);
  hipLaunchKernelGGL(k_conv1, dim3(64, 5, 15), dim3(256), 0, stream, x, w1, spk_pool);
  hipLaunchKernelGGL(k_conv2, dim3(16, 25, 15), dim3(256), 0, stream, spk_pool, w2, pot_out, mp);
  hipLaunchKernelGGL(k_inhib, dim3(256), dim3(64), 0, stream, pot_out, mp, win, nspv, valv, sv);
  hipLaunchKernelGGL(k_select, dim3(1), dim3(256), 0, stream, win, nspv, valv, winners);
  hipMemsetAsync(d_out, 0, (size_t)122880000 * 4, stream);
  hipLaunchKernelGGL(k_scatter, dim3(256), dim3(64), 0, stream, win, sv, spk_out, pot_out);
}